// Round 5
// baseline (325.896 us; speedup 1.0000x reference)
//
#include <hip/hip_runtime.h>

// TripletLossMultipleMargins: mean(relu(|a-p|^2 - |a-n|^2 + M[al, nl]))
// B=1048576, D=64, N_CLASSES=10. Memory-bound streaming reduction.
// R4: NT p/n loads + unroll2 -> 127 us wall = 6.1 TB/s aggregate (97% of
//     6.29 TB/s copy ceiling). HBM itself only ~25% — half served by L3.
// R5: fuse finalize via last-block-wins (threadfence + atomic counter,
//     fixed-order sum -> deterministic); grid 2048->4096 for finer tail.

namespace {
constexpr int kB           = 1048576;
constexpr int kNC          = 10;
constexpr int kBlock       = 256;
constexpr int kLanesPerRow = 16;                     // 16 lanes x float4 = D
constexpr int kRowsPerBlk  = kBlock / kLanesPerRow;  // 16 rows per sub-iteration
constexpr int kUnroll      = 2;
constexpr int kRowsPerIter = kRowsPerBlk * kUnroll;  // 32 rows per block-iteration
constexpr int kGrid        = 4096;                   // kB/(kGrid*kRowsPerIter)=8 iters

typedef float vfloat4 __attribute__((ext_vector_type(4)));
}

__global__ __launch_bounds__(kBlock) void triplet_fused_kernel(
    const vfloat4* __restrict__ a,
    const vfloat4* __restrict__ p,
    const vfloat4* __restrict__ n,
    const int*     __restrict__ alab,
    const int*     __restrict__ nlab,
    const float*   __restrict__ mm,
    float*         __restrict__ partials,
    unsigned int*  __restrict__ counter,
    float*         __restrict__ out)
{
    __shared__ float s_m[kNC * kNC];
    for (int i = threadIdx.x; i < kNC * kNC; i += kBlock) s_m[i] = mm[i];
    __syncthreads();

    const int j   = threadIdx.x & (kLanesPerRow - 1);
    const int rib = threadIdx.x / kLanesPerRow;

    float acc = 0.0f;

    #pragma unroll 1
    for (int base = blockIdx.x * kRowsPerIter; base < kB;
         base += kGrid * kRowsPerIter) {
        const int r0 = base + rib;

        vfloat4 av[kUnroll], pv[kUnroll], nv[kUnroll];
        #pragma unroll
        for (int u = 0; u < kUnroll; ++u) {
            const int idx = (r0 + u * kRowsPerBlk) * kLanesPerRow + j;
            av[u] = a[idx];                              // normal: may L3-persist
            pv[u] = __builtin_nontemporal_load(&p[idx]); // NT: stream
            nv[u] = __builtin_nontemporal_load(&n[idx]); // NT: stream
        }

        int al[kUnroll], nl[kUnroll];
        if (j == 0) {
            #pragma unroll
            for (int u = 0; u < kUnroll; ++u) {
                const int r = r0 + u * kRowsPerBlk;
                al[u] = alab[r];
                nl[u] = nlab[r];
            }
        }

        float diff[kUnroll];
        #pragma unroll
        for (int u = 0; u < kUnroll; ++u) {
            float d, dp = 0.0f, dn = 0.0f;
            d = av[u].x - pv[u].x; dp = fmaf(d, d, dp);
            d = av[u].y - pv[u].y; dp = fmaf(d, d, dp);
            d = av[u].z - pv[u].z; dp = fmaf(d, d, dp);
            d = av[u].w - pv[u].w; dp = fmaf(d, d, dp);
            d = av[u].x - nv[u].x; dn = fmaf(d, d, dn);
            d = av[u].y - nv[u].y; dn = fmaf(d, d, dn);
            d = av[u].z - nv[u].z; dn = fmaf(d, d, dn);
            d = av[u].w - nv[u].w; dn = fmaf(d, d, dn);
            diff[u] = dp - dn;
        }

        #pragma unroll
        for (int m = 8; m >= 1; m >>= 1) {
            #pragma unroll
            for (int u = 0; u < kUnroll; ++u)
                diff[u] += __shfl_xor(diff[u], m, 64);
        }

        if (j == 0) {
            #pragma unroll
            for (int u = 0; u < kUnroll; ++u) {
                const float loss = diff[u] + s_m[al[u] * kNC + nl[u]];
                acc += (loss > 0.0f) ? loss : 0.0f;
            }
        }
    }

    // ---- block reduction ----
    #pragma unroll
    for (int m = 32; m >= 1; m >>= 1) acc += __shfl_xor(acc, m, 64);
    __shared__ float s_red[kBlock / 64];
    __shared__ bool  s_last;
    if ((threadIdx.x & 63) == 0) s_red[threadIdx.x >> 6] = acc;
    __syncthreads();
    if (threadIdx.x == 0) {
        float s = 0.0f;
        #pragma unroll
        for (int w = 0; w < kBlock / 64; ++w) s += s_red[w];
        partials[blockIdx.x] = s;
        __threadfence();  // make partial visible device-wide before signaling
        const unsigned int old = atomicAdd(counter, 1u);
        s_last = (old == (unsigned int)(kGrid - 1));
    }
    __syncthreads();

    // ---- last-arriving block finalizes (fixed summation order -> deterministic) ----
    if (s_last) {
        __threadfence();  // acquire: see all blocks' partials
        float facc = 0.0f;
        #pragma unroll 1
        for (int i = threadIdx.x; i < kGrid; i += kBlock) facc += partials[i];
        #pragma unroll
        for (int m = 32; m >= 1; m >>= 1) facc += __shfl_xor(facc, m, 64);
        if ((threadIdx.x & 63) == 0) s_red[threadIdx.x >> 6] = facc;
        __syncthreads();
        if (threadIdx.x == 0) {
            out[0] = (s_red[0] + s_red[1] + s_red[2] + s_red[3]) * (1.0f / (float)kB);
        }
    }
}

extern "C" void kernel_launch(void* const* d_in, const int* in_sizes, int n_in,
                              void* d_out, int out_size, void* d_ws, size_t ws_size,
                              hipStream_t stream) {
    const vfloat4* a    = (const vfloat4*)d_in[0];
    const vfloat4* p    = (const vfloat4*)d_in[1];
    const vfloat4* n    = (const vfloat4*)d_in[2];
    const int*     alab = (const int*)d_in[3];
    const int*     nlab = (const int*)d_in[4];
    const float*   mm   = (const float*)d_in[5];

    float*        partials = (float*)d_ws;              // kGrid floats
    unsigned int* counter  = (unsigned int*)((char*)d_ws + kGrid * sizeof(float));
    float*        out      = (float*)d_out;

    // counter must be 0 at kernel start each call (ws is poisoned, not re-zeroed)
    hipMemsetAsync(counter, 0, sizeof(unsigned int), stream);

    triplet_fused_kernel<<<kGrid, kBlock, 0, stream>>>(
        a, p, n, alab, nlab, mm, partials, counter, out);
}

// Round 6
// 123.543 us; speedup vs baseline: 2.6379x; 2.6379x over previous
//
#include <hip/hip_runtime.h>

// TripletLossMultipleMargins: mean(relu(|a-p|^2 - |a-n|^2 + M[al, nl]))
// B=1048576, D=64, N_CLASSES=10. Memory-bound streaming reduction.
// R4 (this version): 127.2 us wall = 6.40 TB/s effective on the 813.6 MB
//   stream — at the 6.29 TB/s empirical copy ceiling. FETCH_SIZE ~397 MB is
//   the gfx94x-formula 2x undercount, NOT cache residency.
// R5 lesson (reverted): fused last-block finalize needs per-block agent-scope
//   __threadfence -> L2 wb/inv per block -> 2.5x regression. Keep the tiny
//   separate finalize kernel.

namespace {
constexpr int kB           = 1048576;
constexpr int kNC          = 10;
constexpr int kBlock       = 256;
constexpr int kLanesPerRow = 16;                     // 16 lanes x float4 = D
constexpr int kRowsPerBlk  = kBlock / kLanesPerRow;  // 16 rows per sub-iteration
constexpr int kUnroll      = 2;
constexpr int kRowsPerIter = kRowsPerBlk * kUnroll;  // 32 rows per block-iteration
constexpr int kGrid        = 2048;                   // kB/(kGrid*kRowsPerIter)=16 iters

typedef float vfloat4 __attribute__((ext_vector_type(4)));
}

__global__ __launch_bounds__(kBlock) void triplet_partial_kernel(
    const vfloat4* __restrict__ a,
    const vfloat4* __restrict__ p,
    const vfloat4* __restrict__ n,
    const int*     __restrict__ alab,
    const int*     __restrict__ nlab,
    const float*   __restrict__ mm,
    float*         __restrict__ partials)
{
    __shared__ float s_m[kNC * kNC];
    for (int i = threadIdx.x; i < kNC * kNC; i += kBlock) s_m[i] = mm[i];
    __syncthreads();

    const int j   = threadIdx.x & (kLanesPerRow - 1);
    const int rib = threadIdx.x / kLanesPerRow;

    float acc = 0.0f;

    #pragma unroll 1
    for (int base = blockIdx.x * kRowsPerIter; base < kB;
         base += kGrid * kRowsPerIter) {
        const int r0 = base + rib;

        vfloat4 av[kUnroll], pv[kUnroll], nv[kUnroll];
        #pragma unroll
        for (int u = 0; u < kUnroll; ++u) {
            const int idx = (r0 + u * kRowsPerBlk) * kLanesPerRow + j;
            av[u] = a[idx];
            pv[u] = __builtin_nontemporal_load(&p[idx]);
            nv[u] = __builtin_nontemporal_load(&n[idx]);
        }

        int al[kUnroll], nl[kUnroll];
        if (j == 0) {
            #pragma unroll
            for (int u = 0; u < kUnroll; ++u) {
                const int r = r0 + u * kRowsPerBlk;
                al[u] = alab[r];
                nl[u] = nlab[r];
            }
        }

        float diff[kUnroll];
        #pragma unroll
        for (int u = 0; u < kUnroll; ++u) {
            float d, dp = 0.0f, dn = 0.0f;
            d = av[u].x - pv[u].x; dp = fmaf(d, d, dp);
            d = av[u].y - pv[u].y; dp = fmaf(d, d, dp);
            d = av[u].z - pv[u].z; dp = fmaf(d, d, dp);
            d = av[u].w - pv[u].w; dp = fmaf(d, d, dp);
            d = av[u].x - nv[u].x; dn = fmaf(d, d, dn);
            d = av[u].y - nv[u].y; dn = fmaf(d, d, dn);
            d = av[u].z - nv[u].z; dn = fmaf(d, d, dn);
            d = av[u].w - nv[u].w; dn = fmaf(d, d, dn);
            diff[u] = dp - dn;
        }

        #pragma unroll
        for (int m = 8; m >= 1; m >>= 1) {
            #pragma unroll
            for (int u = 0; u < kUnroll; ++u)
                diff[u] += __shfl_xor(diff[u], m, 64);
        }

        if (j == 0) {
            #pragma unroll
            for (int u = 0; u < kUnroll; ++u) {
                const float loss = diff[u] + s_m[al[u] * kNC + nl[u]];
                acc += (loss > 0.0f) ? loss : 0.0f;
            }
        }
    }

    #pragma unroll
    for (int m = 32; m >= 1; m >>= 1) acc += __shfl_xor(acc, m, 64);
    __shared__ float s_red[kBlock / 64];
    if ((threadIdx.x & 63) == 0) s_red[threadIdx.x >> 6] = acc;
    __syncthreads();
    if (threadIdx.x == 0) {
        float s = 0.0f;
        #pragma unroll
        for (int w = 0; w < kBlock / 64; ++w) s += s_red[w];
        partials[blockIdx.x] = s;
    }
}

__global__ __launch_bounds__(256) void triplet_finalize_kernel(
    const float* __restrict__ partials, float* __restrict__ out, int g)
{
    float acc = 0.0f;
    for (int i = threadIdx.x; i < g; i += 256) acc += partials[i];
    #pragma unroll
    for (int m = 32; m >= 1; m >>= 1) acc += __shfl_xor(acc, m, 64);
    __shared__ float s_red[4];
    if ((threadIdx.x & 63) == 0) s_red[threadIdx.x >> 6] = acc;
    __syncthreads();
    if (threadIdx.x == 0) {
        out[0] = (s_red[0] + s_red[1] + s_red[2] + s_red[3]) * (1.0f / (float)kB);
    }
}

extern "C" void kernel_launch(void* const* d_in, const int* in_sizes, int n_in,
                              void* d_out, int out_size, void* d_ws, size_t ws_size,
                              hipStream_t stream) {
    const vfloat4* a    = (const vfloat4*)d_in[0];
    const vfloat4* p    = (const vfloat4*)d_in[1];
    const vfloat4* n    = (const vfloat4*)d_in[2];
    const int*     alab = (const int*)d_in[3];
    const int*     nlab = (const int*)d_in[4];
    const float*   mm   = (const float*)d_in[5];

    float* partials = (float*)d_ws;           // kGrid floats, fully overwritten
    float* out      = (float*)d_out;

    triplet_partial_kernel<<<kGrid, kBlock, 0, stream>>>(a, p, n, alab, nlab, mm, partials);
    triplet_finalize_kernel<<<1, 256, 0, stream>>>(partials, out, kGrid);
}